// Round 2
// baseline (83.938 us; speedup 1.0000x reference)
//
#include <hip/hip_runtime.h>

#define B_DIM 256
#define E_DIM 8192
#define C_DIM 19
#define XBLK  32                 // E_DIM / B_DIM
#define NBLK  (XBLK * C_DIM)     // 608 blocks in k2's grid

// ws layout (floats), all plain writes except the int ticket:
//  [0    .. 607 ]  capP[c*32+x]  partial count of (e_true>=0.5) over j-slice
//  [608  .. 626 ]  n_pos[c]      count of (y_true>=0.5) over B   (written by k2 x==0)
//  [627  .. 645 ]  sum_yp[c]     sum of y_pred over B            (written by k2 x==0)
//  [646  .. 1253]  mP[c*32+x]    partial weighted pair sum
//  [1254]          ticket        int, zeroed by k1, atomicAdd'd by k2 blocks
#define WS_CAP    0
#define WS_NPOS   608
#define WS_SYP    627
#define WS_M      646
#define WS_TICKET 1254

// Block-wide sum (256 threads = 4 waves). Result valid on tid==0 only.
__device__ __forceinline__ float block_sum(float v, int tid, float* red4) {
    #pragma unroll
    for (int off = 32; off > 0; off >>= 1) v += __shfl_down(v, off, 64);
    if ((tid & 63) == 0) red4[tid >> 6] = v;
    __syncthreads();
    float r = 0.0f;
    if (tid == 0) r = red4[0] + red4[1] + red4[2] + red4[3];
    __syncthreads();
    return r;
}

// K1: grid (32,19) x 256. Per-class partial cap counts ONLY (the B-reductions
// moved into k2 x==0 blocks — their consumer is k2's last-block fold).
// Block (0,0) also zeroes the fold ticket; the kernel boundary publishes it,
// so k2 always sees ticket==0 regardless of harness ws poisoning.
// NOTE (R7 lesson): no prefetch of k2's arrays — harness input-restore leaves
// all inputs L2-warm already; prefetch only lengthens k1's critical path.
__global__ void __launch_bounds__(B_DIM)
rocstar_k1(const float* __restrict__ epoch_true,
           float* __restrict__ ws) {
    const int c   = blockIdx.y;
    const int x   = blockIdx.x;
    const int tid = threadIdx.x;
    const int j   = x * B_DIM + tid;
    __shared__ float red4[4];

    const float cnt = (epoch_true[j * C_DIM + c] >= 0.5f) ? 1.0f : 0.0f;
    const float cs  = block_sum(cnt, tid, red4);
    if (tid == 0) {
        ws[WS_CAP + c * XBLK + x] = cs;
        if (x == 0 && c == 0) ((int*)ws)[WS_TICKET] = 0;
    }
}

// K2: grid (32,19) x 256. Double-compacted pair sums (measured-best R6 form):
//  j-axis: only ~p*256 threads have w!=0 -> ballot-compact {a,s} into s_act.
//  i-axis: s=+1 (epoch neg) needs pm=1 rows only; s=-1 needs pm=0 rows only ->
//          compact yp into pos/neg lists, sentinel-padded so the relu kills pads.
// Inner loop: 3 VALU/element over ~max(np,nn) elements, ~one active wave.
// x==0 blocks also produce n_pos/sum_yp (they load yp/yt anyway), and the
// LAST block to finish (device atomic ticket) performs the old k3 fold
// in-place — deadlock-free (no spinning, no co-residency assumption),
// bitwise-identical numerics (fold code replicated from the old k3 verbatim).
__global__ void __launch_bounds__(B_DIM)
rocstar_k2(const float* __restrict__ y_pred,
           const float* __restrict__ y_true,
           const float* __restrict__ epoch_pred,
           const float* __restrict__ epoch_true,
           const float* __restrict__ gamma,
           const float* __restrict__ rand_pos,
           const float* __restrict__ rand_neg,
           float* __restrict__ ws,
           float* __restrict__ out) {
    const int c   = blockIdx.y;
    const int x   = blockIdx.x;
    const int tid = threadIdx.x;
    const int j   = x * B_DIM + tid;
    const int wv  = tid >> 6;
    const int ln  = tid & 63;

    __shared__ __align__(8) float s_pos[B_DIM];  // yp where pm=1, pad +1e30
    __shared__ __align__(8) float s_neg[B_DIM];  // yp where pm=0, pad -1e30
    __shared__ float2 s_act[B_DIM];              // {a, s} of active j's
    __shared__ int    s_pcnt[4], s_acnt[4];
    __shared__ float  red4[4];
    __shared__ int    s_last;

    // ---- per-thread loads (L2-warm via harness input restore) ----
    const float yp  = y_pred[tid * C_DIM + c];
    const bool  pmb = (y_true[tid * C_DIM + c] >= 0.5f);

    // B-reductions for the fold (block-uniform branch; same block_sum shape as
    // the old k1 -> bitwise-identical n_pos / sum_yp values).
    if (x == 0) {
        const float np = block_sum(pmb ? 1.0f : 0.0f, tid, red4);
        if (tid == 0) ws[WS_NPOS + c] = np;
        const float sy = block_sum(yp, tid, red4);
        if (tid == 0) ws[WS_SYP + c] = sy;
    }

    float cap = 0.0f;
    #pragma unroll
    for (int t = 0; t < XBLK; ++t) cap += ws[WS_CAP + c * XBLK + t];
    const float p = 1000.0f / fmaxf(cap, 1.0f);   // MAX_POS / cap_pos (f32, as ref)
    const float g = gamma[c];

    const float ep = epoch_pred[j * C_DIM + c];
    const bool  et = epoch_true[j * C_DIM + c] >= 0.5f;
    const float rp = rand_pos[j * C_DIM + c];
    const float rn = rand_neg[j * C_DIM + c];

    // faithful to the reference "bug": both masks use p from cap_pos
    const bool  act = (et ? rp : rn) < p;
    // et=0 (epoch neg, m2): d = (ep - yp) + g vs pm=1 rows -> s = +1
    // et=1 (epoch pos, m3): d = (yp - ep) + g vs pm=0 rows -> s = -1
    const float s = et ? -1.0f : 1.0f;
    const float a = fmaf(s, ep, g);               // s*ep + g

    // ---- ballots & per-wave counts ----
    const unsigned long long pmask = __ballot(pmb);
    const unsigned long long amask = __ballot(act);
    if (ln == 0) { s_pcnt[wv] = __popcll(pmask); s_acnt[wv] = __popcll(amask); }
    __syncthreads();

    int posBase = 0, actBase = 0, np = 0, total = 0;
    #pragma unroll
    for (int wk = 0; wk < 4; ++wk) {
        const int pc = s_pcnt[wk], ac = s_acnt[wk];
        np    += pc;
        total += ac;
        if (wk < wv) { posBase += pc; actBase += ac; }
    }
    const int negBase = (wv << 6) - posBase;      // 64*wv - pos_prefix
    const unsigned long long lt = (1ull << ln) - 1ull;
    const int prank = __popcll(pmask & lt);
    const int arank = __popcll(amask & lt);

    // ---- scatter compacted data ----
    if (pmb) s_pos[posBase + prank]        = yp;
    else     s_neg[negBase + (ln - prank)] = yp;
    if (act) s_act[actBase + arank] = make_float2(a, s);

    // ---- sentinel pads (relu kills them: s=+1 reads d=a-yp, s=-1 reads d=a+yp)
    const int nn   = B_DIM - np;
    const int mx   = (np > nn) ? np : nn;
    const int trip = (mx + 1) >> 1;
    const int lim  = trip << 1;                   // <= 256
    if (tid >= np && tid < lim) s_pos[tid] =  1.0e30f;
    if (tid >= nn && tid < lim) s_neg[tid] = -1.0e30f;
    __syncthreads();

    // ---- compacted inner loop (typically ~62 of 256 threads, ~68 f2 iters) ----
    float acc0 = 0.0f, acc1 = 0.0f;
    if (tid < total) {
        const float2 as   = s_act[tid];
        const float  nsgn = -as.y;
        const float2* lst = (as.y > 0.0f) ? (const float2*)s_pos
                                          : (const float2*)s_neg;
        #pragma unroll 4
        for (int k = 0; k < trip; ++k) {
            const float2 v = lst[k];              // 2-address broadcast: free
            float d0 = fmaxf(fmaf(nsgn, v.x, as.x), 0.0f);
            acc0 = fmaf(d0, d0, acc0);
            float d1 = fmaxf(fmaf(nsgn, v.y, as.x), 0.0f);
            acc1 = fmaf(d1, d1, acc1);
        }
    }

    const float bs = block_sum(acc0 + acc1, tid, red4);
    if (tid == 0) ws[WS_M + c * XBLK + x] = bs;

    // ---- last-block fold (replaces the old k3; saves one dispatch) ----
    if (tid == 0) {
        __threadfence();                                   // release our ws stores
        const int t = atomicAdd((int*)ws + WS_TICKET, 1);  // device-scope
        s_last = (t == NBLK - 1) ? 1 : 0;
    }
    __syncthreads();
    if (s_last) {
        __threadfence();   // acquire: all 607 other blocks' stores now visible
        float r = 0.0f;
        if (tid < C_DIM) {
            float m = 0.0f;
            #pragma unroll
            for (int t = 0; t < XBLK; ++t) m += ws[WS_M + tid * XBLK + t];
            float v = m / 1000.0f;                  // m2/MAX_POS + m3/MAX_NEG
            if (isnan(v)) v = 0.0f;
            const float npos = ws[WS_NPOS + tid];
            r = (npos == 0.0f || npos == (float)B_DIM)
                    ? ws[WS_SYP + tid] * 1e-8f      // degenerate: sum(yp)*1e-8
                    : v;
        }
        if (tid < 64) {
            #pragma unroll
            for (int off = 16; off > 0; off >>= 1) r += __shfl_down(r, off, 64);
            if (tid == 0) out[0] = r / (float)C_DIM;    // mean over classes
        }
    }
}

extern "C" void kernel_launch(void* const* d_in, const int* in_sizes, int n_in,
                              void* d_out, int out_size, void* d_ws, size_t ws_size,
                              hipStream_t stream) {
    const float* y_pred     = (const float*)d_in[0];
    const float* y_true     = (const float*)d_in[1];
    const float* epoch_pred = (const float*)d_in[2];
    const float* epoch_true = (const float*)d_in[3];
    const float* gamma      = (const float*)d_in[4];
    const float* rand_pos   = (const float*)d_in[5];
    const float* rand_neg   = (const float*)d_in[6];
    float*       out        = (float*)d_out;
    float*       ws         = (float*)d_ws;

    const dim3 grid(XBLK, C_DIM);   // 32 x 19
    rocstar_k1<<<grid, B_DIM, 0, stream>>>(epoch_true, ws);
    rocstar_k2<<<grid, B_DIM, 0, stream>>>(y_pred, y_true, epoch_pred, epoch_true,
                                           gamma, rand_pos, rand_neg, ws, out);
}

// Round 3
// 82.084 us; speedup vs baseline: 1.0226x; 1.0226x over previous
//
#include <hip/hip_runtime.h>

#define B_DIM 256
#define E_DIM 8192
#define C_DIM 19
#define XBLK  32                 // E_DIM / B_DIM
#define NBLK  (XBLK * C_DIM)     // 608 blocks in k2's grid

// ws layout (floats):
//  [0    .. 607 ]  capP[c*32+x]  partial count of (e_true>=0.5) over j-slice (k1, plain)
//  [608  .. 626 ]  n_pos[c]      count of (y_true>=0.5) over B   (k1, plain)
//  [627  .. 645 ]  sum_yp[c]     sum of y_pred over B            (k1, plain)
//  [646  .. 1253]  mP[c*32+x]    partial pair sums (k2, ATOMIC publish — coherent
//                                cross-XCD without threadfence/wbl2; R2 lesson:
//                                plain-store+__threadfence cost +9us in L2 writebacks)
//  [1254]          ticket        int, zeroed by k1, atomicAdd'd by k2 blocks
#define WS_CAP    0
#define WS_NPOS   608
#define WS_SYP    627
#define WS_M      646
#define WS_TICKET 1254

// Block-wide sum (256 threads = 4 waves). Result valid on tid==0 only.
__device__ __forceinline__ float block_sum(float v, int tid, float* red4) {
    #pragma unroll
    for (int off = 32; off > 0; off >>= 1) v += __shfl_down(v, off, 64);
    if ((tid & 63) == 0) red4[tid >> 6] = v;
    __syncthreads();
    float r = 0.0f;
    if (tid == 0) r = red4[0] + red4[1] + red4[2] + red4[3];
    __syncthreads();
    return r;
}

// K1: exactly the proven R0 form (74.9us session-best): per-class partial cap
// counts; block x==0 also does the B-reductions (n_pos, sum_yp). Plain writes;
// the kernel boundary publishes them device-wide (free batched writeback).
// Block (0,0) additionally zeroes the fold ticket.
// NOTE (R7 lesson): no prefetch of k2's arrays — harness input-restore leaves
// all inputs L2-warm already; prefetch only lengthens k1's critical path.
__global__ void __launch_bounds__(B_DIM)
rocstar_k1(const float* __restrict__ y_pred,
           const float* __restrict__ y_true,
           const float* __restrict__ epoch_true,
           float* __restrict__ ws) {
    const int c   = blockIdx.y;
    const int x   = blockIdx.x;
    const int tid = threadIdx.x;
    const int j   = x * B_DIM + tid;
    __shared__ float red4[4];

    const float cnt = (epoch_true[j * C_DIM + c] >= 0.5f) ? 1.0f : 0.0f;
    const float cs  = block_sum(cnt, tid, red4);
    if (tid == 0) {
        ws[WS_CAP + c * XBLK + x] = cs;
        if (x == 0 && c == 0) ((int*)ws)[WS_TICKET] = 0;
    }

    if (x == 0) {
        const float ypv = y_pred[tid * C_DIM + c];
        const float ytv = (y_true[tid * C_DIM + c] >= 0.5f) ? 1.0f : 0.0f;
        const float np  = block_sum(ytv, tid, red4);
        if (tid == 0) ws[WS_NPOS + c] = np;
        const float sy  = block_sum(ypv, tid, red4);
        if (tid == 0) ws[WS_SYP + c] = sy;
    }
}

// K2: grid (32,19) x 256. Double-compacted pair sums (measured-best R6 form),
// unchanged. NEW (fence-free k3 absorption):
//  - block partial published via atomicExch (device-scope atomics are coherent
//    across XCDs per-address; no L2 writeback involved),
//  - tid0 consumes the exch return value -> compiler emits s_waitcnt on it ->
//    the publish has REACHED the coherent point before the ticket bump,
//  - the 608th ticket holder folds, reading partials via atomicAdd(p, +0.0f)
//    (coherent load; partials are >= +0.0 so +0.0f is exact) in the SAME
//    t=0..31 order as the old k3 -> bitwise-identical result.
// No spinning, no co-residency assumption, no threadfence.
__global__ void __launch_bounds__(B_DIM)
rocstar_k2(const float* __restrict__ y_pred,
           const float* __restrict__ y_true,
           const float* __restrict__ epoch_pred,
           const float* __restrict__ epoch_true,
           const float* __restrict__ gamma,
           const float* __restrict__ rand_pos,
           const float* __restrict__ rand_neg,
           float* __restrict__ ws,
           float* __restrict__ out) {
    const int c   = blockIdx.y;
    const int x   = blockIdx.x;
    const int tid = threadIdx.x;
    const int j   = x * B_DIM + tid;
    const int wv  = tid >> 6;
    const int ln  = tid & 63;

    __shared__ __align__(8) float s_pos[B_DIM];  // yp where pm=1, pad +1e30
    __shared__ __align__(8) float s_neg[B_DIM];  // yp where pm=0, pad -1e30
    __shared__ float2 s_act[B_DIM];              // {a, s} of active j's
    __shared__ int    s_pcnt[4], s_acnt[4];
    __shared__ float  red4[4];
    __shared__ int    s_last;

    // ---- per-thread loads (L2-warm via harness input restore) ----
    const float yp  = y_pred[tid * C_DIM + c];
    const bool  pmb = (y_true[tid * C_DIM + c] >= 0.5f);

    float cap = 0.0f;
    #pragma unroll
    for (int t = 0; t < XBLK; ++t) cap += ws[WS_CAP + c * XBLK + t];
    const float p = 1000.0f / fmaxf(cap, 1.0f);   // MAX_POS / cap_pos (f32, as ref)
    const float g = gamma[c];

    const float ep = epoch_pred[j * C_DIM + c];
    const bool  et = epoch_true[j * C_DIM + c] >= 0.5f;
    const float rp = rand_pos[j * C_DIM + c];
    const float rn = rand_neg[j * C_DIM + c];

    // faithful to the reference "bug": both masks use p from cap_pos
    const bool  act = (et ? rp : rn) < p;
    // et=0 (epoch neg, m2): d = (ep - yp) + g vs pm=1 rows -> s = +1
    // et=1 (epoch pos, m3): d = (yp - ep) + g vs pm=0 rows -> s = -1
    const float s = et ? -1.0f : 1.0f;
    const float a = fmaf(s, ep, g);               // s*ep + g

    // ---- ballots & per-wave counts ----
    const unsigned long long pmask = __ballot(pmb);
    const unsigned long long amask = __ballot(act);
    if (ln == 0) { s_pcnt[wv] = __popcll(pmask); s_acnt[wv] = __popcll(amask); }
    __syncthreads();

    int posBase = 0, actBase = 0, np = 0, total = 0;
    #pragma unroll
    for (int wk = 0; wk < 4; ++wk) {
        const int pc = s_pcnt[wk], ac = s_acnt[wk];
        np    += pc;
        total += ac;
        if (wk < wv) { posBase += pc; actBase += ac; }
    }
    const int negBase = (wv << 6) - posBase;      // 64*wv - pos_prefix
    const unsigned long long lt = (1ull << ln) - 1ull;
    const int prank = __popcll(pmask & lt);
    const int arank = __popcll(amask & lt);

    // ---- scatter compacted data ----
    if (pmb) s_pos[posBase + prank]        = yp;
    else     s_neg[negBase + (ln - prank)] = yp;
    if (act) s_act[actBase + arank] = make_float2(a, s);

    // ---- sentinel pads (relu kills them: s=+1 reads d=a-yp, s=-1 reads d=a+yp)
    const int nn   = B_DIM - np;
    const int mx   = (np > nn) ? np : nn;
    const int trip = (mx + 1) >> 1;
    const int lim  = trip << 1;                   // <= 256
    if (tid >= np && tid < lim) s_pos[tid] =  1.0e30f;
    if (tid >= nn && tid < lim) s_neg[tid] = -1.0e30f;
    __syncthreads();

    // ---- compacted inner loop (typically ~62 of 256 threads, ~68 f2 iters) ----
    float acc0 = 0.0f, acc1 = 0.0f;
    if (tid < total) {
        const float2 as   = s_act[tid];
        const float  nsgn = -as.y;
        const float2* lst = (as.y > 0.0f) ? (const float2*)s_pos
                                          : (const float2*)s_neg;
        #pragma unroll 4
        for (int k = 0; k < trip; ++k) {
            const float2 v = lst[k];              // 2-address broadcast: free
            float d0 = fmaxf(fmaf(nsgn, v.x, as.x), 0.0f);
            acc0 = fmaf(d0, d0, acc0);
            float d1 = fmaxf(fmaf(nsgn, v.y, as.x), 0.0f);
            acc1 = fmaf(d1, d1, acc1);
        }
    }

    const float bs = block_sum(acc0 + acc1, tid, red4);

    // ---- fence-free publish + ticket ----
    if (tid == 0) {
        const float old = atomicExch(&ws[WS_M + c * XBLK + x], bs);
        // consume the return value: forces the s_waitcnt on the atomic response,
        // i.e. the publish reached the coherent point before the ticket bump.
        __asm__ __volatile__("" :: "v"(old));
        const int t = atomicAdd((int*)ws + WS_TICKET, 1);
        s_last = (t == NBLK - 1) ? 1 : 0;
    }
    __syncthreads();

    // ---- last-arriver fold (the old k3, verbatim order; coherent atomic loads)
    if (s_last) {
        float r = 0.0f;
        if (tid < C_DIM) {
            float m = 0.0f;
            #pragma unroll
            for (int t = 0; t < XBLK; ++t)
                m += atomicAdd(&ws[WS_M + tid * XBLK + t], 0.0f);  // coherent load
            float v = m / 1000.0f;                  // m2/MAX_POS + m3/MAX_NEG
            if (isnan(v)) v = 0.0f;
            const float npos = ws[WS_NPOS + tid];   // k1-written: boundary-coherent
            r = (npos == 0.0f || npos == (float)B_DIM)
                    ? ws[WS_SYP + tid] * 1e-8f      // degenerate: sum(yp)*1e-8
                    : v;
        }
        if (tid < 64) {
            #pragma unroll
            for (int off = 16; off > 0; off >>= 1) r += __shfl_down(r, off, 64);
            if (tid == 0) out[0] = r / (float)C_DIM;    // mean over classes
        }
    }
}

extern "C" void kernel_launch(void* const* d_in, const int* in_sizes, int n_in,
                              void* d_out, int out_size, void* d_ws, size_t ws_size,
                              hipStream_t stream) {
    const float* y_pred     = (const float*)d_in[0];
    const float* y_true     = (const float*)d_in[1];
    const float* epoch_pred = (const float*)d_in[2];
    const float* epoch_true = (const float*)d_in[3];
    const float* gamma      = (const float*)d_in[4];
    const float* rand_pos   = (const float*)d_in[5];
    const float* rand_neg   = (const float*)d_in[6];
    float*       out        = (float*)d_out;
    float*       ws         = (float*)d_ws;

    const dim3 grid(XBLK, C_DIM);   // 32 x 19
    rocstar_k1<<<grid, B_DIM, 0, stream>>>(y_pred, y_true, epoch_true, ws);
    rocstar_k2<<<grid, B_DIM, 0, stream>>>(y_pred, y_true, epoch_pred, epoch_true,
                                           gamma, rand_pos, rand_neg, ws, out);
}